// Round 9
// baseline (640.447 us; speedup 1.0000x reference)
//
#include <hip/hip_runtime.h>

#define P 16384
#define S 4096
#define NB 8
#define CAP 16

typedef unsigned long long u64;
typedef unsigned int u32;

// Opaque identity: forces separate rounding, blocks fma contraction across it.
#define OPAQUE(x) __asm__("" : "+v"(x))

// pd (f32, ref formula) -> u32 key monotone DESCENDING in pd; (dk<<32)|idx in
// ascending u64 order reproduces jax.lax.top_k (largest pd, ties->lower idx).
__device__ __forceinline__ u32 pd_to_dk(float pd) {
  pd = pd + 0.0f;                        // canonicalize -0 -> +0
  u32 b = __float_as_uint(pd);
  u32 s = (u32)((int)b >> 31);
  return b ^ (~(s | 0x80000000u));       // neg: b ; non-neg: b ^ 0x7FFFFFFF
}
__device__ __forceinline__ float dk_to_pd(u32 d) {
  u32 pb = (d & 0x80000000u) ? d : (d ^ 0x7FFFFFFFu);
  return __uint_as_float(pb);            // sentinel 0xFF800000 -> -inf
}
// 2-ulp step toward -inf; conservative lower bound for threshold transform.
__device__ __forceinline__ float prev2(float v) {
  u32 b = __float_as_uint(v);
  if ((b & 0x7F800000u) == 0x7F800000u) return v;   // +-inf: keep
  if (v > 0.0f) b -= 2;
  else if (v < 0.0f) b += 2;
  else return -1e-30f;
  return __uint_as_float(b);
}

__device__ __forceinline__ void insert16(u64 (&L)[16], u64 key) {
#pragma unroll
  for (int j = 15; j >= 1; --j) {
    u64 a = (L[j - 1] > key) ? L[j - 1] : key;
    L[j] = (L[j] > key) ? a : L[j];
  }
  L[0] = (L[0] > key) ? key : L[0];
}

// ---------------- Kernel A: per-batch min/max of channels 0,1 ----------------
__global__ void kminmax(const float* __restrict__ x, float* __restrict__ mm) {
  int b = blockIdx.x;
  int tid = threadIdx.x;
  const float* x0 = x + (size_t)b * 5 * P;
  const float* x1 = x0 + P;
  float mn0 = __builtin_inff(), mx0 = -__builtin_inff();
  float mn1 = __builtin_inff(), mx1 = -__builtin_inff();
  for (int i = tid; i < P; i += 256) {
    float a = x0[i];
    mn0 = fminf(mn0, a); mx0 = fmaxf(mx0, a);
    float c = x1[i];
    mn1 = fminf(mn1, c); mx1 = fmaxf(mx1, c);
  }
  __shared__ float s0[256], s1[256], s2[256], s3[256];
  s0[tid] = mn0; s1[tid] = mx0; s2[tid] = mn1; s3[tid] = mx1;
  __syncthreads();
  for (int off = 128; off > 0; off >>= 1) {
    if (tid < off) {
      s0[tid] = fminf(s0[tid], s0[tid + off]);
      s1[tid] = fmaxf(s1[tid], s1[tid + off]);
      s2[tid] = fminf(s2[tid], s2[tid + off]);
      s3[tid] = fmaxf(s3[tid], s3[tid + off]);
    }
    __syncthreads();
  }
  if (tid == 0) {
    mm[b * 4 + 0] = s0[0];
    mm[b * 4 + 1] = s1[0];
    mm[b * 4 + 2] = s2[0];
    mm[b * 4 + 3] = s3[0];
  }
}

// ---------------- Kernel P: precompute xx (2D and 3D), exact ref roundings --
__global__ void kprep(const float* __restrict__ x, float* __restrict__ xx2d,
                      float* __restrict__ xx3d) {
#pragma clang fp contract(off)
  int gid = blockIdx.x * 256 + threadIdx.x;   // 0 .. NB*P-1
  int b = gid >> 14;
  int i = gid & (P - 1);
  const float* xs = x + (size_t)b * 5 * P;
  float x0 = xs[i], x1 = xs[P + i], x2 = xs[2 * P + i];
  float t0 = x0 * x0; OPAQUE(t0);
  float t1 = x1 * x1; OPAQUE(t1);
  float t2 = x2 * x2; OPAQUE(t2);
  float s2 = t0 + t1;
  xx2d[gid] = s2;
  xx3d[gid] = s2 + t2;
}

// ---------------- Kernel B: 1-NN in 2D, 4-way candidate split ---------------
// grid NB*64*4: (b, sgrp, quarter); 4 waves scan 1024 cands each.
__global__ __launch_bounds__(256) void kidx1(const float* __restrict__ x,
                                             const float* __restrict__ mm,
                                             const float* __restrict__ xx2d,
                                             u64* __restrict__ bests1) {
#pragma clang fp contract(off)
  int blk = blockIdx.x;
  int b = blk >> 8;
  int sgrp = (blk >> 2) & 63;
  int qtr = blk & 3;
  int w = threadIdx.x >> 6, l = threadIdx.x & 63;
  const float* xs = x + (size_t)b * 5 * P;
  const float* ys = xs + P;
  float mn0 = mm[b * 4 + 0], mx0 = mm[b * 4 + 1];
  float mn1 = mm[b * 4 + 2], mx1 = mm[b * 4 + 3];
  float m0 = (float)l * (1.0f / 64.0f);
  float m1 = (float)sgrp * (1.0f / 64.0f);
  float d0 = mx0 - mn0, d1 = mx1 - mn1;
  float p0 = m0 * d0; OPAQUE(p0);
  float q0 = p0 + mn0;
  float p1 = m1 * d1; OPAQUE(p1);
  float q1 = p1 + mn1;
  float sq0 = q0 * q0; OPAQUE(sq0);
  float sq1 = q1 * q1; OPAQUE(sq1);
  float qq = sq0 + sq1;

  int base = qtr * 4096 + w * 1024;
  const float4* xs4 = (const float4*)(xs + base);
  const float4* ys4 = (const float4*)(ys + base);
  const float4* ws4 = (const float4*)(xx2d + b * P + base);
  float best_pd = -__builtin_inff();
  u32 best_idx = 0;
  for (int j = 0; j < 256; ++j) {
    float4 cx = xs4[j];
    float4 cy = ys4[j];
    float4 cw = ws4[j];
    float cxa[4] = {cx.x, cx.y, cx.z, cx.w};
    float cya[4] = {cy.x, cy.y, cy.z, cy.w};
    float cwa[4] = {cw.x, cw.y, cw.z, cw.w};
#pragma unroll
    for (int t = 0; t < 4; ++t) {
      // ip = fma(x1,q1, round(x0*q0)); pd = fma(2,ip,-xx) - qq
      float ip = __builtin_fmaf(cya[t], q1, cxa[t] * q0);
      float a  = __builtin_fmaf(2.0f, ip, -cwa[t]);
      float pd = a - qq;
      bool bt = pd > best_pd;   // strict: ties keep earlier (lower idx)
      best_pd  = bt ? pd : best_pd;
      best_idx = bt ? (u32)(base + (j << 2) + t) : best_idx;
    }
  }
  u64 key = ((u64)pd_to_dk(best_pd) << 32) | best_idx;
  __shared__ u64 kb[4][64];
  kb[w][l] = key;
  __syncthreads();
  if (threadIdx.x < 64) {
    u64 m = kb[0][l];
    u64 t1 = kb[1][l]; m = (t1 < m) ? t1 : m;
    u64 t2 = kb[2][l]; m = (t2 < m) ? t2 : m;
    u64 t3 = kb[3][l]; m = (t3 < m) ? t3 : m;
    bests1[((size_t)((b * 64 + sgrp) * 4 + qtr) << 6) + l] = m;
  }
}

// ---------------- Kernel Q: merge quarters, gather query xyz ----------------
__global__ void kq(const float* __restrict__ x, const u64* __restrict__ bests1,
                   float* __restrict__ qx, float* __restrict__ qy,
                   float* __restrict__ qz) {
  int qi = blockIdx.x * 256 + threadIdx.x;   // 0..NB*S-1
  int b = qi >> 12;
  int s = qi & 4095;
  int sgrp = s >> 6, l = s & 63;
  size_t o = ((size_t)((b * 64 + sgrp) * 4) << 6) + l;
  u64 m = bests1[o];
  u64 t;
  t = bests1[o + 64];  m = (t < m) ? t : m;
  t = bests1[o + 128]; m = (t < m) ? t : m;
  t = bests1[o + 192]; m = (t < m) ? t : m;
  u32 idx = (u32)m;
  const float* xs = x + (size_t)b * 5 * P;
  qx[qi] = xs[idx];
  qy[qi] = xs[P + idx];
  qz[qi] = xs[2 * P + idx];
}

// ---------------- Kernel C: 16-NN in 3D, geometric drain schedule -----------
// 512 threads; 8 waves x 2048-cand chunks; drains at fixed ~sqrt(2)-spaced j.
__global__ __launch_bounds__(512) void kidx2(const float* __restrict__ x,
                                             const float* __restrict__ xx3d,
                                             const float* __restrict__ qx,
                                             const float* __restrict__ qy,
                                             const float* __restrict__ qz,
                                             float* __restrict__ out) {
#pragma clang fp contract(off)
  __shared__ u64 buf[512][CAP + 1];   // 69.6 KB; +1 pad breaks bank aliasing
  __shared__ u64 mgf[64][17];         // 8.7 KB merged lists
  int b = blockIdx.x >> 6, sgrp = blockIdx.x & 63;
  int w = threadIdx.x >> 6, l = threadIdx.x & 63;
  int s = (sgrp << 6) + l;
  int qi = (b << 12) + s;
  float q0 = qx[qi], q1 = qy[qi], q2 = qz[qi];
  float sq0 = q0 * q0; OPAQUE(sq0);
  float sq1 = q1 * q1; OPAQUE(sq1);
  float sq2 = q2 * q2; OPAQUE(sq2);
  float qq = (sq0 + sq1) + sq2;
  const float* xs = x + (size_t)b * 5 * P;
  const float* ys = xs + P;
  const float* zs = xs + 2 * P;
  int base = w * 2048;
  const float4* xs4 = (const float4*)(xs + base);
  const float4* ys4 = (const float4*)(ys + base);
  const float4* zs4 = (const float4*)(zs + base);
  const float4* ws4 = (const float4*)(xx3d + b * P + base);

  u64 L[16];
#pragma unroll
  for (int k = 0; k < 16; ++k) L[k] = 0xFF800000FFFFFFFFull;  // dk(-inf)|idx
  // Accept test in a-space: a = fma(2,ip,-xx); pd = a - qq (monotone in a).
  // thrA = prev2(thr_pd + qq): 2-ulp conservative; over-accepts filtered
  // exactly in the drain.
  float thrA = -__builtin_inff();
  int cnt = 0;
  u64* bufp = buf[threadIdx.x];

  auto drain = [&]() {
    while (__any(cnt > 0)) {
      if (cnt > 0) {
        --cnt;
        u64 e = bufp[cnt];
        float pd = __uint_as_float((u32)(e >> 32)) - qq;  // exact ref rounding
        u64 key = ((u64)pd_to_dk(pd) << 32) | (u32)e;
        if (key < L[15]) insert16(L, key);
      }
    }
    float tp = dk_to_pd((u32)(L[15] >> 32));
    thrA = prev2(tp + qq);     // -inf stays -inf
  };

  // One j = 4 candidates. Eval is bit-identical to r7; pushes buffered;
  // overflow (cnt==CAP, astronomically rare) falls back to exact direct
  // insert so correctness never depends on the schedule.
#define KBODY { \
    float4 cx = xs4[j]; float4 cy = ys4[j]; \
    float4 cz = zs4[j]; float4 cw = ws4[j]; \
    float cxa[4] = {cx.x, cx.y, cx.z, cx.w}; \
    float cya[4] = {cy.x, cy.y, cy.z, cy.w}; \
    float cza[4] = {cz.x, cz.y, cz.z, cz.w}; \
    float cwa[4] = {cw.x, cw.y, cw.z, cw.w}; \
    _Pragma("unroll") \
    for (int t = 0; t < 4; ++t) { \
      float ip = __builtin_fmaf(cza[t], q2, \
                                __builtin_fmaf(cya[t], q1, cxa[t] * q0)); \
      float a  = __builtin_fmaf(2.0f, ip, -cwa[t]); \
      if (a >= thrA) { \
        if (cnt < CAP) { \
          bufp[cnt] = ((u64)__float_as_uint(a) << 32) | (u32)(base + (j << 2) + t); \
          ++cnt; \
        } else { \
          float pd = a - qq; \
          u64 key = ((u64)pd_to_dk(pd) << 32) | (u32)(base + (j << 2) + t); \
          if (key < L[15]) insert16(L, key); \
        } \
      } \
    } }

#define WINDOW(JE) { for (; j < (JE); ++j) KBODY drain(); }

  int j = 0;
  WINDOW(4)   WINDOW(6)   WINDOW(8)   WINDOW(11)  WINDOW(16)
  WINDOW(23)  WINDOW(32)  WINDOW(45)  WINDOW(64)  WINDOW(91)
  WINDOW(128) WINDOW(181) WINDOW(256) WINDOW(362) WINDOW(512)
#undef WINDOW
#undef KBODY

  // lists -> buf rows (cnt==0 everywhere; rows are free, 16 <= CAP+1)
#pragma unroll
  for (int k = 0; k < 16; ++k) bufp[k] = L[k];
  __syncthreads();

  if (w == 0) {
    // 8-way lazy merge for query l: lists live at rows {wv*64+l}
    int p0 = 0, p1 = 0, p2 = 0, p3 = 0, p4 = 0, p5 = 0, p6 = 0, p7 = 0;
    u64 h0 = buf[l][0],        h1 = buf[64 + l][0];
    u64 h2 = buf[128 + l][0],  h3 = buf[192 + l][0];
    u64 h4 = buf[256 + l][0],  h5 = buf[320 + l][0];
    u64 h6 = buf[384 + l][0],  h7 = buf[448 + l][0];
#define ADV(i) { ++p##i; h##i = (p##i < 16) ? buf[i * 64 + l][p##i] : ~0ULL; }
    for (int k = 0; k < 16; ++k) {
      u64 m01 = (h0 < h1) ? h0 : h1;
      u64 m23 = (h2 < h3) ? h2 : h3;
      u64 m45 = (h4 < h5) ? h4 : h5;
      u64 m67 = (h6 < h7) ? h6 : h7;
      u64 ma = (m01 < m23) ? m01 : m23;
      u64 mb = (m45 < m67) ? m45 : m67;
      u64 m = (ma < mb) ? ma : mb;
      mgf[l][k] = m;
      if      (m == h0) ADV(0)
      else if (m == h1) ADV(1)
      else if (m == h2) ADV(2)
      else if (m == h3) ADV(3)
      else if (m == h4) ADV(4)
      else if (m == h5) ADV(5)
      else if (m == h6) ADV(6)
      else              ADV(7)
    }
#undef ADV
  }
  __syncthreads();

  // epilogue: thread -> (query row, k-pair); coalesced float2 stores
  int qrow = threadIdx.x >> 3;
  int g = threadIdx.x & 7;
  int sOut = (sgrp << 6) + qrow;
  u32 i0 = (u32)mgf[qrow][g * 2 + 0];
  u32 i1 = (u32)mgf[qrow][g * 2 + 1];
#pragma unroll
  for (int c = 0; c < 5; ++c) {
    const float* xc = x + (size_t)(b * 5 + c) * P;
    float2 v;
    v.x = xc[i0]; v.y = xc[i1];
    float* op = out + (((size_t)(b * 5 + c) * S + sOut) << 4) + (g << 1);
    *(float2*)op = v;
  }
}

extern "C" void kernel_launch(void* const* d_in, const int* in_sizes, int n_in,
                              void* d_out, int out_size, void* d_ws, size_t ws_size,
                              hipStream_t stream) {
  const float* x = (const float*)d_in[0];
  float* out = (float*)d_out;
  char* ws = (char*)d_ws;
  float* mm    = (float*)ws;                         // 1 KB
  float* xx2d  = (float*)(ws + 1024);                // 512 KB
  float* xx3d  = (float*)(ws + 1024 + 524288);       // 512 KB
  u64*   bests1= (u64*)  (ws + 1024 + 2 * 524288);   // NB*64*4*64 u64 = 1 MB
  float* qx    = (float*)(ws + 1024 + 2 * 524288 + 1048576);  // 128 KB
  float* qy    = qx + NB * S;
  float* qz    = qy + NB * S;

  kminmax<<<NB, 256, 0, stream>>>(x, mm);
  kprep<<<NB * P / 256, 256, 0, stream>>>(x, xx2d, xx3d);
  kidx1<<<NB * 256, 256, 0, stream>>>(x, mm, xx2d, bests1);
  kq<<<NB * S / 256, 256, 0, stream>>>(x, bests1, qx, qy, qz);
  kidx2<<<NB * 64, 512, 0, stream>>>(x, xx3d, qx, qy, qz, out);
}